// Round 1
// baseline (3462.425 us; speedup 1.0000x reference)
//
#include <hip/hip_runtime.h>
#include <hip/hip_bf16.h>

#define BATCH 4096
#define DIM   512
#define HID   2048
#define NSTEPS 20

typedef __attribute__((ext_vector_type(8))) short short8;
typedef __attribute__((ext_vector_type(4))) short short4v;
typedef __attribute__((ext_vector_type(4))) float floatx4;

#define GLL(dst, src) __builtin_amdgcn_global_load_lds( \
    (const __attribute__((address_space(1))) void*)(src), \
    (__attribute__((address_space(3))) void*)(dst), 16, 0, 0)

__device__ __forceinline__ short f2bf(float x) {
    union { float f; unsigned u; } v; v.f = x;
    unsigned r = v.u + 0x7fffu + ((v.u >> 16) & 1u);
    return (short)(r >> 16);
}

// tanh(x) = 1 - 2*rcp(1 + exp2(2*log2e*x)); saturates correctly at +-inf
__device__ __forceinline__ float fast_tanh(float x) {
    float e = __builtin_amdgcn_exp2f(x * 2.8853900817779268f);
    float r = __builtin_amdgcn_rcpf(1.0f + e);
    return 1.0f - 2.0f * r;
}

// dst[n][k] = bf16(src[k][n]); src is K x N row-major fp32
__global__ void transpose_cvt(const float* __restrict__ src, short* __restrict__ dst,
                              int K, int N) {
    __shared__ float tile[32][33];
    int k0 = blockIdx.x * 32, n0 = blockIdx.y * 32;
    int tx = threadIdx.x, ty = threadIdx.y;
    #pragma unroll
    for (int r = ty; r < 32; r += 8)
        tile[r][tx] = src[(size_t)(k0 + r) * N + n0 + tx];
    __syncthreads();
    #pragma unroll
    for (int r = ty; r < 32; r += 8)
        dst[(size_t)(n0 + r) * K + k0 + tx] = f2bf(tile[tx][r]);
}

__global__ void extract_row(const float* __restrict__ W1, float* __restrict__ w1last) {
    int i = blockIdx.x * 256 + threadIdx.x;
    w1last[i] = W1[(size_t)DIM * HID + i];
}

__global__ void init_abuf(const float* __restrict__ z0, short* __restrict__ abuf) {
    size_t i = (size_t)(blockIdx.x * 256 + threadIdx.x) * 4;
    float4 zv = *(const float4*)(z0 + i);
    short4v o;
    o[0] = f2bf(zv.x); o[1] = f2bf(zv.y); o[2] = f2bf(zv.z); o[3] = f2bf(zv.w);
    *(short4v*)(abuf + i) = o;
}

// hidden = tanh( A @ W1t^T + b1 + t*w1last ), bf16 out.
// 128x128 tile, BK=64 DOUBLE-BUFFERED (64 KB LDS -> 2 blocks/CU), T3-template
// 2-phase: stage(it+1) -> compute(it) -> syncthreads (drain happens after the
// MFMA phase, hiding most of the staging latency). XOR-swizzled LDS chunks,
// wave-tile 64x64, operand-swapped MFMA for packed epilogue stores.
// XCD-chunked block swizzle: each XCD keeps full W1t (2MB) + 4 abuf slices
// (512 KB) resident in its private L2.
__global__ __launch_bounds__(256, 2)
void gemm1_tanh(const short* __restrict__ A, const short* __restrict__ Bt,
                const float* __restrict__ b1, const float* __restrict__ w1last,
                const float* __restrict__ t0p, const float* __restrict__ t1p,
                float c_t, float step_i,
                short* __restrict__ hidden) {
    __shared__ short Alds[2][128 * 64];   // 2 x 16 KB
    __shared__ short Blds[2][128 * 64];   // 2 x 16 KB
    const int tid = threadIdx.x;
    const int lane = tid & 63;
    const int wave = tid >> 6;
    const int wm = wave >> 1, wn = wave & 1;

    // bijective XCD swizzle (512 blocks % 8 == 0), N varies fastest per chunk
    const int f = blockIdx.x + gridDim.x * blockIdx.y;   // dispatch order id
    const int swz = (f & 7) * 64 + (f >> 3);
    const int bm0 = (swz >> 4) * 128;    // 32 M-blocks
    const int bn0 = (swz & 15) * 128;    // 16 N-blocks

    const float t0 = t0p[0], t1 = t1p[0];
    const float h = (t1 - t0) / (float)NSTEPS;
    const float teval = t0 + (step_i + c_t) * h;

    floatx4 acc[4][4];
    #pragma unroll
    for (int i = 0; i < 4; i++)
        #pragma unroll
        for (int j = 0; j < 4; j++) acc[i][j] = (floatx4)0.f;

    const int fr = lane & 15;
    const int fkc = lane >> 4;     // 0..3
    const int rx = fr & 7;

    // stage one 128x64 tile pair: 1024 chunks of 16B per matrix, 4/thread.
    // physical chunk ci holds global chunk ci^(row&7)  (bank-conflict-free
    // ds_read_b128 on the column-slice reads).
    #define STAGE1(buf, kk) do { \
        _Pragma("unroll") \
        for (int p = 0; p < 4; p++) { \
            const int l = tid + p * 256; \
            const int row = l >> 3; \
            const int g = (l & 7) ^ (row & 7); \
            GLL(&Alds[(buf)][l * 8], A  + (size_t)(bm0 + row) * DIM + (kk) + g * 8); \
            GLL(&Blds[(buf)][l * 8], Bt + (size_t)(bn0 + row) * DIM + (kk) + g * 8); \
        } } while (0)

    STAGE1(0, 0);
    __syncthreads();               // drain: buf0 staged
    #pragma unroll
    for (int it = 0; it < 8; ++it) {           // DIM/64 = 8 K-steps
        const int cur = it & 1;
        if (it < 7) STAGE1(cur ^ 1, (it + 1) * 64);   // prefetch next tile
        #pragma unroll
        for (int s = 0; s < 2; s++) {
            const int lc = s * 4 + fkc;                // logical chunk 0..7
            const int slot = (lc ^ rx) * 8;
            short8 af[4], bfr[4];
            #pragma unroll
            for (int mt = 0; mt < 4; mt++)
                af[mt] = *(const short8*)&Alds[cur][(wm * 64 + mt * 16 + fr) * 64 + slot];
            #pragma unroll
            for (int nt = 0; nt < 4; nt++)
                bfr[nt] = *(const short8*)&Blds[cur][(wn * 64 + nt * 16 + fr) * 64 + slot];
            #pragma unroll
            for (int mt = 0; mt < 4; mt++)
                #pragma unroll
                for (int nt = 0; nt < 4; nt++)   // swapped: lane holds 4 consecutive cols
                    acc[mt][nt] = __builtin_amdgcn_mfma_f32_16x16x32_bf16(bfr[nt], af[mt], acc[mt][nt], 0, 0, 0);
        }
        if (it < 7) __syncthreads();   // drains vmcnt(0): prefetch landed; also
                                       // guards buf overwrite next iteration
    }
    // epilogue: lane = row m (fr); regs = 4 consecutive cols -> packed 8B stores
    #pragma unroll
    for (int mt = 0; mt < 4; mt++) {
        int m = bm0 + wm * 64 + mt * 16 + fr;
        short* hrow = hidden + (size_t)m * HID;
        #pragma unroll
        for (int nt = 0; nt < 4; nt++) {
            int n0 = bn0 + wn * 64 + nt * 16 + fkc * 4;
            float4 bb = *(const float4*)&b1[n0];
            float4 wl = *(const float4*)&w1last[n0];
            short4v o;
            o[0] = f2bf(fast_tanh(acc[mt][nt][0] + bb.x + teval * wl.x));
            o[1] = f2bf(fast_tanh(acc[mt][nt][1] + bb.y + teval * wl.y));
            o[2] = f2bf(fast_tanh(acc[mt][nt][2] + bb.z + teval * wl.z));
            o[3] = f2bf(fast_tanh(acc[mt][nt][3] + bb.w + teval * wl.w));
            *(short4v*)&hrow[n0] = o;
        }
    }
}

// k = hidden @ W2t^T + b2.  64x64 tile, 256 threads = 4-way K-split across
// waves (wave K=512, 16 iters of BK=32), per-wave private DOUBLE-BUFFERED
// 16 KB slab (64 KB total -> 2 blocks/CU), ZERO barriers in the K-loop and a
// COUNTED vmcnt(8): stage(it+1) is issued, then compute(it) runs immediately
// (its data already landed) -- staging never sits on the critical path.
// mode 0 (k1): kacc = k;            abuf = bf16(z + alpha*h*k)
// mode 1 (k2/k3): kacc += wk*k;     abuf = bf16(z + alpha*h*k)
// mode 2 (k4): z += (h/6)*(kacc+k); abuf = bf16(z_new)
__global__ __launch_bounds__(256, 2)
void gemm2_fused(const short* __restrict__ hidden,  // [BATCH][HID] bf16
                 const short* __restrict__ Bt,      // W2t [DIM][HID] bf16
                 const float* __restrict__ b2,
                 float* __restrict__ z,
                 float* __restrict__ kacc, short* __restrict__ abuf,
                 const float* __restrict__ t0p, const float* __restrict__ t1p,
                 int mode, float wk, float alpha_c) {
    __shared__ short lds[4 * 8192];    // 4 waves x 16 KB (dbuf: 2 x (A 4KB + B 4KB))
    const int tid = threadIdx.x;
    const int lane = tid & 63;
    const int wave = tid >> 6;          // K-split index 0..3

    // bijective XCD swizzle (512 blocks), N fastest per chunk: each XCD keeps
    // full W2t (2MB) + 8 hidden M-slices (2MB) in its private L2.
    const int f = blockIdx.x + gridDim.x * blockIdx.y;
    const int swz = (f & 7) * 64 + (f >> 3);
    const int bm0 = (swz >> 3) * 64;    // 64 M-blocks
    const int bn0 = (swz & 7) * 64;     // 8 N-blocks
    const int kbase = wave * 512;

    short* slab = &lds[wave * 8192];    // own 16 KB; buf b at b*4096 shorts

    const int fr = lane & 15;
    const int fkc = lane >> 4;          // 0..3

    floatx4 acc[4][4];
    #pragma unroll
    for (int i = 0; i < 4; i++)
        #pragma unroll
        for (int j = 0; j < 4; j++) acc[i][j] = (floatx4)0.f;

    // stage one 64x32 tile pair into buf b: 256 chunks/matrix, 4/lane.
    // physical chunk ci holds global chunk ci ^ ((row>>1)&3)  (2-bit swizzle;
    // read-side b128 column-slices land conflict-free: 16(row&1)+4(fkc^..)
    // spreads 64 lanes exactly 2-per-bank).
    #define STAGE2(b, k0) do { \
        _Pragma("unroll") \
        for (int j = 0; j < 4; j++) { \
            const int row = j * 16 + (lane >> 2); \
            const int g = (lane & 3) ^ ((lane >> 3) & 3); \
            GLL(slab + (b) * 4096 +        (j * 64 + lane) * 8, \
                hidden + (size_t)(bm0 + row) * HID + (k0) + g * 8); \
            GLL(slab + (b) * 4096 + 2048 + (j * 64 + lane) * 8, \
                Bt     + (size_t)(bn0 + row) * HID + (k0) + g * 8); \
        } } while (0)

    STAGE2(0, kbase);
    #pragma unroll
    for (int it = 0; it < 16; ++it) {
        const int cur = it & 1;
        if (it < 15) {
            STAGE2(cur ^ 1, kbase + (it + 1) * 32);   // 8 GLLs in flight for next
            __builtin_amdgcn_sched_barrier(0);
            __builtin_amdgcn_s_waitcnt(0x0F78);       // vmcnt(8): current buf landed
            __builtin_amdgcn_sched_barrier(0);
        } else {
            __builtin_amdgcn_sched_barrier(0);
            __builtin_amdgcn_s_waitcnt(0x0F70);       // vmcnt(0): last buf landed
            __builtin_amdgcn_sched_barrier(0);
        }
        const short* sa = slab + cur * 4096;
        const short* sb = sa + 2048;
        const int phys = (fkc ^ ((fr >> 1) & 3)) * 8;
        short8 af[4], bfr[4];
        #pragma unroll
        for (int mt = 0; mt < 4; mt++)
            af[mt] = *(const short8*)&sa[(mt * 16 + fr) * 32 + phys];
        #pragma unroll
        for (int nt = 0; nt < 4; nt++)
            bfr[nt] = *(const short8*)&sb[(nt * 16 + fr) * 32 + phys];
        #pragma unroll
        for (int mt = 0; mt < 4; mt++)
            #pragma unroll
            for (int nt = 0; nt < 4; nt++)
                acc[mt][nt] = __builtin_amdgcn_mfma_f32_16x16x32_bf16(af[mt], bfr[nt], acc[mt][nt], 0, 0, 0);
    }

    // write partial acc (fp32 [64][64]) into own slab (exactly 16 KB), then
    // reduce across the 4 waves. float4-chunk XOR swizzle (c4 ^ (row&15))
    // makes both the scalar writes and the float4 reduce reads ~conflict-free.
    __builtin_amdgcn_s_waitcnt(0xC07F);   // lgkmcnt(0): own ds_reads done
    float* fslab = (float*)slab;
    #pragma unroll
    for (int mt = 0; mt < 4; mt++)
        #pragma unroll
        for (int nt = 0; nt < 4; nt++)
            #pragma unroll
            for (int r = 0; r < 4; r++) {
                int row = mt * 16 + fkc * 4 + r;
                int col = nt * 16 + fr;
                int pc4 = (col >> 2) ^ (row & 15);
                fslab[row * 64 + pc4 * 4 + (col & 3)] = acc[mt][nt][r];
            }
    __syncthreads();

    // 256 threads: each handles 1 row x 16 cols
    const int rrow = tid >> 2;          // 0..63
    const int cc = tid & 3;             // 16-col chunk
    float4 v[4];
    #pragma unroll
    for (int q = 0; q < 4; q++) v[q] = make_float4(0.f, 0.f, 0.f, 0.f);
    #pragma unroll
    for (int w = 0; w < 4; w++) {
        const float* fs = (const float*)&lds[w * 8192];
        #pragma unroll
        for (int q = 0; q < 4; q++) {
            int pc4 = (cc * 4 + q) ^ (rrow & 15);
            float4 p = *(const float4*)&fs[rrow * 64 + pc4 * 4];
            v[q].x += p.x; v[q].y += p.y; v[q].z += p.z; v[q].w += p.w;
        }
    }

    const float hh = (t1p[0] - t0p[0]) / (float)NSTEPS;
    const float ah = alpha_c * hh;
    const float h6 = hh / 6.0f;
    const size_t base = (size_t)(bm0 + rrow) * DIM + bn0 + cc * 16;

    float kv[16], zl[16], zn[16];
    #pragma unroll
    for (int q = 0; q < 4; q++) {
        float4 bb = *(const float4*)&b2[bn0 + cc * 16 + q * 4];
        kv[q * 4 + 0] = v[q].x + bb.x;
        kv[q * 4 + 1] = v[q].y + bb.y;
        kv[q * 4 + 2] = v[q].z + bb.z;
        kv[q * 4 + 3] = v[q].w + bb.w;
        float4 zq = *(const float4*)&z[base + q * 4];
        zl[q * 4 + 0] = zq.x; zl[q * 4 + 1] = zq.y;
        zl[q * 4 + 2] = zq.z; zl[q * 4 + 3] = zq.w;
    }
    if (mode == 0) {
        #pragma unroll
        for (int q = 0; q < 4; q++)
            *(float4*)&kacc[base + q * 4] =
                make_float4(kv[q*4], kv[q*4+1], kv[q*4+2], kv[q*4+3]);
        #pragma unroll
        for (int i = 0; i < 16; i++) zn[i] = zl[i] + ah * kv[i];
    } else if (mode == 1) {
        #pragma unroll
        for (int q = 0; q < 4; q++) {
            float4 ka = *(const float4*)&kacc[base + q * 4];
            *(float4*)&kacc[base + q * 4] =
                make_float4(ka.x + wk * kv[q*4],   ka.y + wk * kv[q*4+1],
                            ka.z + wk * kv[q*4+2], ka.w + wk * kv[q*4+3]);
        }
        #pragma unroll
        for (int i = 0; i < 16; i++) zn[i] = zl[i] + ah * kv[i];
    } else {
        #pragma unroll
        for (int q = 0; q < 4; q++) {
            float4 ka = *(const float4*)&kacc[base + q * 4];
            zn[q*4+0] = zl[q*4+0] + h6 * (ka.x + kv[q*4+0]);
            zn[q*4+1] = zl[q*4+1] + h6 * (ka.y + kv[q*4+1]);
            zn[q*4+2] = zl[q*4+2] + h6 * (ka.z + kv[q*4+2]);
            zn[q*4+3] = zl[q*4+3] + h6 * (ka.w + kv[q*4+3]);
            *(float4*)&z[base + q * 4] =
                make_float4(zn[q*4], zn[q*4+1], zn[q*4+2], zn[q*4+3]);
        }
    }
    short8 o0, o1;
    #pragma unroll
    for (int i = 0; i < 8; i++) { o0[i] = f2bf(zn[i]); o1[i] = f2bf(zn[8 + i]); }
    *(short8*)&abuf[base] = o0;
    *(short8*)&abuf[base + 8] = o1;
}

extern "C" void kernel_launch(void* const* d_in, const int* in_sizes, int n_in,
                              void* d_out, int out_size, void* d_ws, size_t ws_size,
                              hipStream_t stream) {
    const float* z0  = (const float*)d_in[0];
    const float* W1  = (const float*)d_in[1];
    const float* b1  = (const float*)d_in[2];
    const float* W2  = (const float*)d_in[3];
    const float* b2  = (const float*)d_in[4];
    const float* t0p = (const float*)d_in[5];
    const float* t1p = (const float*)d_in[6];
    float* z = (float*)d_out;

    char* ws = (char*)d_ws;
    short* W1t    = (short*)(ws);                              // 2 MB
    short* W2t    = (short*)(ws + (2u << 20));                 // 2 MB
    float* w1last = (float*)(ws + (4u << 20));                 // 8 KB (pad 64 KB)
    short* abuf   = (short*)(ws + (4u << 20) + (1u << 16));    // 4 MB
    short* hidden = (short*)(ws + (8u << 20) + (1u << 16));    // 16 MB
    float* kacc   = (float*)(ws + (24u << 20) + (1u << 16));   // 8 MB

    hipMemcpyAsync(z, z0, (size_t)BATCH * DIM * sizeof(float),
                   hipMemcpyDeviceToDevice, stream);
    transpose_cvt<<<dim3(DIM / 32, HID / 32), dim3(32, 8), 0, stream>>>(W1, W1t, DIM, HID);
    transpose_cvt<<<dim3(HID / 32, DIM / 32), dim3(32, 8), 0, stream>>>(W2, W2t, HID, DIM);
    extract_row<<<HID / 256, 256, 0, stream>>>(W1, w1last);
    init_abuf<<<BATCH * DIM / 4 / 256, 256, 0, stream>>>(z0, abuf);

    const dim3 g1(BATCH / 128, HID / 128), g2(BATCH / 64, DIM / 64);
    const dim3 b1d(256), b2d(256);
    for (int i = 0; i < NSTEPS; i++) {
        float fi = (float)i;
        // k1 -> abuf for k2
        gemm1_tanh<<<g1, b1d, 0, stream>>>(abuf, W1t, b1, w1last, t0p, t1p, 0.0f, fi, hidden);
        gemm2_fused<<<g2, b2d, 0, stream>>>(hidden, W2t, b2, z, kacc, abuf, t0p, t1p, 0, 1.0f, 0.5f);
        // k2 -> abuf for k3
        gemm1_tanh<<<g1, b1d, 0, stream>>>(abuf, W1t, b1, w1last, t0p, t1p, 0.5f, fi, hidden);
        gemm2_fused<<<g2, b2d, 0, stream>>>(hidden, W2t, b2, z, kacc, abuf, t0p, t1p, 1, 2.0f, 0.5f);
        // k3 -> abuf for k4
        gemm1_tanh<<<g1, b1d, 0, stream>>>(abuf, W1t, b1, w1last, t0p, t1p, 0.5f, fi, hidden);
        gemm2_fused<<<g2, b2d, 0, stream>>>(hidden, W2t, b2, z, kacc, abuf, t0p, t1p, 1, 2.0f, 1.0f);
        // k4: z += (h/6)*(kacc + k4) ; abuf = bf16(z_new)
        gemm1_tanh<<<g1, b1d, 0, stream>>>(abuf, W1t, b1, w1last, t0p, t1p, 1.0f, fi, hidden);
        gemm2_fused<<<g2, b2d, 0, stream>>>(hidden, W2t, b2, z, kacc, abuf, t0p, t1p, 2, 1.0f, 0.0f);
    }
}

// Round 2
// 3158.035 us; speedup vs baseline: 1.0964x; 1.0964x over previous
//
#include <hip/hip_runtime.h>
#include <hip/hip_bf16.h>

#define BATCH 4096
#define DIM   512
#define HID   2048
#define NSTEPS 20

typedef __attribute__((ext_vector_type(8))) short short8;
typedef __attribute__((ext_vector_type(4))) short short4v;
typedef __attribute__((ext_vector_type(4))) float floatx4;

#define GLL(dst, src) __builtin_amdgcn_global_load_lds( \
    (const __attribute__((address_space(1))) void*)(src), \
    (__attribute__((address_space(3))) void*)(dst), 16, 0, 0)

__device__ __forceinline__ short f2bf(float x) {
    union { float f; unsigned u; } v; v.f = x;
    unsigned r = v.u + 0x7fffu + ((v.u >> 16) & 1u);
    return (short)(r >> 16);
}

// tanh(x) = 1 - 2*rcp(1 + exp2(2*log2e*x)); saturates correctly at +-inf
__device__ __forceinline__ float fast_tanh(float x) {
    float e = __builtin_amdgcn_exp2f(x * 2.8853900817779268f);
    float r = __builtin_amdgcn_rcpf(1.0f + e);
    return 1.0f - 2.0f * r;
}

// dst[n][k] = bf16(src[k][n]); src is K x N row-major fp32
__global__ void transpose_cvt(const float* __restrict__ src, short* __restrict__ dst,
                              int K, int N) {
    __shared__ float tile[32][33];
    int k0 = blockIdx.x * 32, n0 = blockIdx.y * 32;
    int tx = threadIdx.x, ty = threadIdx.y;
    #pragma unroll
    for (int r = ty; r < 32; r += 8)
        tile[r][tx] = src[(size_t)(k0 + r) * N + n0 + tx];
    __syncthreads();
    #pragma unroll
    for (int r = ty; r < 32; r += 8)
        dst[(size_t)(n0 + r) * K + k0 + tx] = f2bf(tile[tx][r]);
}

__global__ void extract_row(const float* __restrict__ W1, float* __restrict__ w1last) {
    int i = blockIdx.x * 256 + threadIdx.x;
    w1last[i] = W1[(size_t)DIM * HID + i];
}

__global__ void init_abuf(const float* __restrict__ z0, short* __restrict__ abuf) {
    size_t i = (size_t)(blockIdx.x * 256 + threadIdx.x) * 4;
    float4 zv = *(const float4*)(z0 + i);
    short4v o;
    o[0] = f2bf(zv.x); o[1] = f2bf(zv.y); o[2] = f2bf(zv.z); o[3] = f2bf(zv.w);
    *(short4v*)(abuf + i) = o;
}

// hidden = tanh( A @ W1t^T + b1 + t*w1last ), bf16 out.
// ROUND-0 PROVEN VERSION (verbatim): 128x128 tile, BK=128, XOR-swizzled LDS,
// wave-tile 64x64, 2 blocks/CU, operand-swapped MFMA epilogue.
__global__ __launch_bounds__(256, 2)
void gemm1_tanh(const short* __restrict__ A, const short* __restrict__ Bt,
                const float* __restrict__ b1, const float* __restrict__ w1last,
                const float* __restrict__ t0p, const float* __restrict__ t1p,
                float c_t, float step_i,
                short* __restrict__ hidden) {
    __shared__ short Alds[128 * 128];   // 32 KB
    __shared__ short Blds[128 * 128];   // 32 KB
    const int tid = threadIdx.x;
    const int lane = tid & 63;
    const int wave = tid >> 6;
    const int wm = wave >> 1, wn = wave & 1;
    const int bm0 = blockIdx.x * 128;   // 32 blocks over M
    const int bn0 = blockIdx.y * 128;   // 16 blocks over N

    const float t0 = t0p[0], t1 = t1p[0];
    const float h = (t1 - t0) / (float)NSTEPS;
    const float teval = t0 + (step_i + c_t) * h;

    floatx4 acc[4][4];
    #pragma unroll
    for (int i = 0; i < 4; i++)
        #pragma unroll
        for (int j = 0; j < 4; j++) acc[i][j] = (floatx4)0.f;

    const int fr = lane & 15;
    const int fkc = lane >> 4;     // 0..3
    const int rx = fr & 7;

    for (int kk = 0; kk < DIM; kk += 128) {
        // stage A,B tiles 128x128: 2048 chunks of 16B each, 8/thread
        #pragma unroll
        for (int p = 0; p < 8; p++) {
            int c = tid + p * 256;
            int row = c >> 4;
            int ci = c & 15;
            int g = ((ci & 7) ^ (row & 7)) | (ci & 8);   // swizzle low 3 bits
            GLL(&Alds[c * 8], A  + (size_t)(bm0 + row) * DIM + kk + g * 8);
            GLL(&Blds[c * 8], Bt + (size_t)(bn0 + row) * DIM + kk + g * 8);
        }
        __syncthreads();               // forced vmcnt(0): staging landed
        #pragma unroll
        for (int s = 0; s < 4; s++) {
            const int lc = s * 4 + fkc;                       // logical chunk 0..15
            const int slot = ((((lc & 7) ^ rx) | (lc & 8))) * 8;
            short8 af[4], bfr[4];
            #pragma unroll
            for (int mt = 0; mt < 4; mt++)
                af[mt] = *(const short8*)&Alds[(wm * 64 + mt * 16 + fr) * 128 + slot];
            #pragma unroll
            for (int nt = 0; nt < 4; nt++)
                bfr[nt] = *(const short8*)&Blds[(wn * 64 + nt * 16 + fr) * 128 + slot];
            #pragma unroll
            for (int mt = 0; mt < 4; mt++)
                #pragma unroll
                for (int nt = 0; nt < 4; nt++)   // swapped: lane holds 4 consecutive cols
                    acc[mt][nt] = __builtin_amdgcn_mfma_f32_16x16x32_bf16(bfr[nt], af[mt], acc[mt][nt], 0, 0, 0);
        }
        __syncthreads();
    }
    // epilogue: lane = row m (fr); regs = 4 consecutive cols -> packed 8B stores
    #pragma unroll
    for (int mt = 0; mt < 4; mt++) {
        int m = bm0 + wm * 64 + mt * 16 + fr;
        short* hrow = hidden + (size_t)m * HID;
        #pragma unroll
        for (int nt = 0; nt < 4; nt++) {
            int n0 = bn0 + wn * 64 + nt * 16 + fkc * 4;
            float4 bb = *(const float4*)&b1[n0];
            float4 wl = *(const float4*)&w1last[n0];
            short4v o;
            o[0] = f2bf(fast_tanh(acc[mt][nt][0] + bb.x + teval * wl.x));
            o[1] = f2bf(fast_tanh(acc[mt][nt][1] + bb.y + teval * wl.y));
            o[2] = f2bf(fast_tanh(acc[mt][nt][2] + bb.z + teval * wl.z));
            o[3] = f2bf(fast_tanh(acc[mt][nt][3] + bb.w + teval * wl.w));
            *(short4v*)&hrow[n0] = o;
        }
    }
}

// k = hidden @ W2t^T + b2.  Block tile 128x64 (two 64-row M-halves), 512 thr
// = 8-way K-split across waves (wave K=256, 8 iters of BK=32). Each wave
// computes BOTH M-halves against ONE shared staged B slab -> per-iter staging
// 12 KB (A0+A1+B) instead of 2x16 KB for the same output: block stages 768 KB
// for 128x64 out (round-0: 1 MB per 128x64) => -28% GEMM2 traffic. Grid 256
// blocks = exactly 1/CU (no 2-round tail). ZERO barriers in the K-loop:
// per-wave private slabs, decoupled waves self-stagger (round-0 dynamics).
// Reduce over the 8 K-partials runs twice (once per M-half), reusing the
// 128 KB LDS.
// mode 0 (k1): kacc = k;            abuf = bf16(z + alpha*h*k)
// mode 1 (k2/k3): kacc += wk*k;     abuf = bf16(z + alpha*h*k)
// mode 2 (k4): z += (h/6)*(kacc+k); abuf = bf16(z_new)
__global__ __launch_bounds__(512, 2)
void gemm2_fused(const short* __restrict__ hidden,  // [BATCH][HID] bf16
                 const short* __restrict__ Bt,      // W2t [DIM][HID] bf16
                 const float* __restrict__ b2,
                 float* __restrict__ z,
                 float* __restrict__ kacc, short* __restrict__ abuf,
                 const float* __restrict__ t0p, const float* __restrict__ t1p,
                 int mode, float wk, float alpha_c) {
    __shared__ short lds[65536];        // 128 KB: staging 8x12KB, reduce 8x16KB
    const int tid = threadIdx.x;
    const int lane = tid & 63;
    const int wave = tid >> 6;          // K-split index 0..7
    const int bm0 = blockIdx.x * 128;   // 32 blocks over M
    const int bn0 = blockIdx.y * 64;    // 8 blocks over N
    const int kbase = wave * 256;

    // per-wave staging slabs: A0 64x32, A1 64x32, B 64x32 (4 KB each)
    short* slabA0 = &lds[wave * 6144];
    short* slabA1 = slabA0 + 2048;
    short* slabB  = slabA0 + 4096;

    const int fr = lane & 15;
    const int fkc = lane >> 4;          // 0..3
    const int l2b = (lane >> 3) & 3;    // staging swizzle bits
    const int gch = (lane & 3) ^ l2b;   // swizzled global k-chunk
    const int srow = lane >> 2;         // staging row within 16-row group
    const int phys = (fkc ^ ((fr >> 1) & 3)) * 8;   // read-side swizzled chunk

    floatx4 acc0[4][4], acc1[4][4];
    #pragma unroll
    for (int i = 0; i < 4; i++)
        #pragma unroll
        for (int j = 0; j < 4; j++) { acc0[i][j] = (floatx4)0.f; acc1[i][j] = (floatx4)0.f; }

    #pragma unroll
    for (int it = 0; it < 8; ++it) {
        const int k0 = kbase + it * 32;
        // drain own ds_reads before overwriting slabs (lgkmcnt(0))
        __builtin_amdgcn_s_waitcnt(0xC07F);
        __builtin_amdgcn_sched_barrier(0);
        #pragma unroll
        for (int j = 0; j < 4; j++) {
            const int row = j * 16 + srow;
            GLL(&slabA0[j * 512 + lane * 8], hidden + (size_t)(bm0 + row) * HID + k0 + gch * 8);
            GLL(&slabA1[j * 512 + lane * 8], hidden + (size_t)(bm0 + 64 + row) * HID + k0 + gch * 8);
            GLL(&slabB [j * 512 + lane * 8], Bt     + (size_t)(bn0 + row) * HID + k0 + gch * 8);
        }
        __builtin_amdgcn_sched_barrier(0);
        __builtin_amdgcn_s_waitcnt(0x0F70);   // vmcnt(0) only, per-wave
        __builtin_amdgcn_sched_barrier(0);
        short8 bfrg[4];
        #pragma unroll
        for (int nt = 0; nt < 4; nt++)
            bfrg[nt] = *(const short8*)&slabB[(nt * 16 + fr) * 32 + phys];
        {
            short8 af[4];
            #pragma unroll
            for (int mt = 0; mt < 4; mt++)
                af[mt] = *(const short8*)&slabA0[(mt * 16 + fr) * 32 + phys];
            #pragma unroll
            for (int mt = 0; mt < 4; mt++)
                #pragma unroll
                for (int nt = 0; nt < 4; nt++)
                    acc0[mt][nt] = __builtin_amdgcn_mfma_f32_16x16x32_bf16(af[mt], bfrg[nt], acc0[mt][nt], 0, 0, 0);
        }
        {
            short8 af[4];
            #pragma unroll
            for (int mt = 0; mt < 4; mt++)
                af[mt] = *(const short8*)&slabA1[(mt * 16 + fr) * 32 + phys];
            #pragma unroll
            for (int mt = 0; mt < 4; mt++)
                #pragma unroll
                for (int nt = 0; nt < 4; nt++)
                    acc1[mt][nt] = __builtin_amdgcn_mfma_f32_16x16x32_bf16(af[mt], bfrg[nt], acc1[mt][nt], 0, 0, 0);
        }
        __builtin_amdgcn_sched_barrier(0);
    }

    __builtin_amdgcn_s_waitcnt(0xC07F);   // lgkmcnt(0): own ds_reads done
    __syncthreads();

    const float hh = (t1p[0] - t0p[0]) / (float)NSTEPS;
    const float ah = alpha_c * hh;
    const float h6 = hh / 6.0f;
    const int rrow = tid >> 3;          // 0..63
    const int c8 = (tid & 7) * 8;       // col chunk of 8
    float4 bb0 = *(const float4*)&b2[bn0 + c8];
    float4 bb1 = *(const float4*)&b2[bn0 + c8 + 4];

    // two passes: m-half 0 (acc0) then m-half 1 (acc1)
    #pragma unroll
    for (int mh = 0; mh < 2; mh++) {
        // write this half's partial acc (fp32 [64][64]) into own 16 KB region
        float* fslab = (float*)&lds[wave * 8192];
        #pragma unroll
        for (int mt = 0; mt < 4; mt++)
            #pragma unroll
            for (int nt = 0; nt < 4; nt++)
                #pragma unroll
                for (int r = 0; r < 4; r++) {
                    int row = mt * 16 + fkc * 4 + r;
                    int col = nt * 16 + fr;
                    fslab[row * 64 + col] = (mh == 0) ? acc0[mt][nt][r] : acc1[mt][nt][r];
                }
        __syncthreads();

        // 512 threads: each handles 1 row x 8 cols; sum 8 K-partials
        float4 v0 = make_float4(0.f, 0.f, 0.f, 0.f);
        float4 v1 = make_float4(0.f, 0.f, 0.f, 0.f);
        #pragma unroll
        for (int w = 0; w < 8; w++) {
            const float* fs = (const float*)&lds[w * 8192];
            float4 p0 = *(const float4*)&fs[rrow * 64 + c8];
            float4 p1 = *(const float4*)&fs[rrow * 64 + c8 + 4];
            v0.x += p0.x; v0.y += p0.y; v0.z += p0.z; v0.w += p0.w;
            v1.x += p1.x; v1.y += p1.y; v1.z += p1.z; v1.w += p1.w;
        }

        const size_t base = (size_t)(bm0 + mh * 64 + rrow) * DIM + bn0 + c8;
        float kv[8] = { v0.x + bb0.x, v0.y + bb0.y, v0.z + bb0.z, v0.w + bb0.w,
                        v1.x + bb1.x, v1.y + bb1.y, v1.z + bb1.z, v1.w + bb1.w };
        float4 zv0 = *(const float4*)&z[base];
        float4 zv1 = *(const float4*)&z[base + 4];
        float zl[8] = { zv0.x, zv0.y, zv0.z, zv0.w, zv1.x, zv1.y, zv1.z, zv1.w };
        float zn[8];
        if (mode == 0) {
            *(float4*)&kacc[base]     = make_float4(kv[0], kv[1], kv[2], kv[3]);
            *(float4*)&kacc[base + 4] = make_float4(kv[4], kv[5], kv[6], kv[7]);
            #pragma unroll
            for (int i = 0; i < 8; i++) zn[i] = zl[i] + ah * kv[i];
        } else if (mode == 1) {
            float4 ka0 = *(const float4*)&kacc[base];
            float4 ka1 = *(const float4*)&kacc[base + 4];
            *(float4*)&kacc[base]     = make_float4(ka0.x + wk * kv[0], ka0.y + wk * kv[1],
                                                    ka0.z + wk * kv[2], ka0.w + wk * kv[3]);
            *(float4*)&kacc[base + 4] = make_float4(ka1.x + wk * kv[4], ka1.y + wk * kv[5],
                                                    ka1.z + wk * kv[6], ka1.w + wk * kv[7]);
            #pragma unroll
            for (int i = 0; i < 8; i++) zn[i] = zl[i] + ah * kv[i];
        } else {
            float4 ka0 = *(const float4*)&kacc[base];
            float4 ka1 = *(const float4*)&kacc[base + 4];
            float kaf[8] = { ka0.x, ka0.y, ka0.z, ka0.w, ka1.x, ka1.y, ka1.z, ka1.w };
            #pragma unroll
            for (int i = 0; i < 8; i++) zn[i] = zl[i] + h6 * (kaf[i] + kv[i]);
            *(float4*)&z[base]     = make_float4(zn[0], zn[1], zn[2], zn[3]);
            *(float4*)&z[base + 4] = make_float4(zn[4], zn[5], zn[6], zn[7]);
        }
        short4v o0, o1;
        o0[0] = f2bf(zn[0]); o0[1] = f2bf(zn[1]); o0[2] = f2bf(zn[2]); o0[3] = f2bf(zn[3]);
        o1[0] = f2bf(zn[4]); o1[1] = f2bf(zn[5]); o1[2] = f2bf(zn[6]); o1[3] = f2bf(zn[7]);
        *(short4v*)&abuf[base]     = o0;
        *(short4v*)&abuf[base + 4] = o1;
        if (mh == 0) __syncthreads();   // reads of pass-0 partials done before overwrite
    }
}

extern "C" void kernel_launch(void* const* d_in, const int* in_sizes, int n_in,
                              void* d_out, int out_size, void* d_ws, size_t ws_size,
                              hipStream_t stream) {
    const float* z0  = (const float*)d_in[0];
    const float* W1  = (const float*)d_in[1];
    const float* b1  = (const float*)d_in[2];
    const float* W2  = (const float*)d_in[3];
    const float* b2  = (const float*)d_in[4];
    const float* t0p = (const float*)d_in[5];
    const float* t1p = (const float*)d_in[6];
    float* z = (float*)d_out;

    char* ws = (char*)d_ws;
    short* W1t    = (short*)(ws);                              // 2 MB
    short* W2t    = (short*)(ws + (2u << 20));                 // 2 MB
    float* w1last = (float*)(ws + (4u << 20));                 // 8 KB (pad 64 KB)
    short* abuf   = (short*)(ws + (4u << 20) + (1u << 16));    // 4 MB
    short* hidden = (short*)(ws + (8u << 20) + (1u << 16));    // 16 MB
    float* kacc   = (float*)(ws + (24u << 20) + (1u << 16));   // 8 MB

    hipMemcpyAsync(z, z0, (size_t)BATCH * DIM * sizeof(float),
                   hipMemcpyDeviceToDevice, stream);
    transpose_cvt<<<dim3(DIM / 32, HID / 32), dim3(32, 8), 0, stream>>>(W1, W1t, DIM, HID);
    transpose_cvt<<<dim3(HID / 32, DIM / 32), dim3(32, 8), 0, stream>>>(W2, W2t, HID, DIM);
    extract_row<<<HID / 256, 256, 0, stream>>>(W1, w1last);
    init_abuf<<<BATCH * DIM / 4 / 256, 256, 0, stream>>>(z0, abuf);

    const dim3 g1(BATCH / 128, HID / 128), g2(BATCH / 128, DIM / 64);
    const dim3 b1d(256), b2d(512);
    for (int i = 0; i < NSTEPS; i++) {
        float fi = (float)i;
        // k1 -> abuf for k2
        gemm1_tanh<<<g1, b1d, 0, stream>>>(abuf, W1t, b1, w1last, t0p, t1p, 0.0f, fi, hidden);
        gemm2_fused<<<g2, b2d, 0, stream>>>(hidden, W2t, b2, z, kacc, abuf, t0p, t1p, 0, 1.0f, 0.5f);
        // k2 -> abuf for k3
        gemm1_tanh<<<g1, b1d, 0, stream>>>(abuf, W1t, b1, w1last, t0p, t1p, 0.5f, fi, hidden);
        gemm2_fused<<<g2, b2d, 0, stream>>>(hidden, W2t, b2, z, kacc, abuf, t0p, t1p, 1, 2.0f, 0.5f);
        // k3 -> abuf for k4
        gemm1_tanh<<<g1, b1d, 0, stream>>>(abuf, W1t, b1, w1last, t0p, t1p, 0.5f, fi, hidden);
        gemm2_fused<<<g2, b2d, 0, stream>>>(hidden, W2t, b2, z, kacc, abuf, t0p, t1p, 1, 2.0f, 1.0f);
        // k4: z += (h/6)*(kacc + k4) ; abuf = bf16(z_new)
        gemm1_tanh<<<g1, b1d, 0, stream>>>(abuf, W1t, b1, w1last, t0p, t1p, 1.0f, fi, hidden);
        gemm2_fused<<<g2, b2d, 0, stream>>>(hidden, W2t, b2, z, kacc, abuf, t0p, t1p, 2, 1.0f, 0.0f);
    }
}